// Round 5
// baseline (760.278 us; speedup 1.0000x reference)
//
#include <hip/hip_runtime.h>
#include <hip/hip_bf16.h>

// Problem constants (from reference setup_inputs)
#define F_SIZE 1024
#define E_DIM  128
#define N_D    6000
#define N_SE   1000
#define N_TOT  7000
#define M_TPL  300000
#define LAMB   1e-6f
#define KPAD   7040   // N_TOT rounded up (xT leading dim)

typedef __bf16 bf16x8 __attribute__((ext_vector_type(8)));
typedef float  f32x4  __attribute__((ext_vector_type(4)));
typedef unsigned short u16;

__device__ __forceinline__ float hshrink(float v) {
    return fabsf(v) > LAMB ? v : 0.0f;
}

// RNE float -> bf16 bits (inputs are finite; no NaN handling needed)
__device__ __forceinline__ u16 f2bf(float f) {
    unsigned int u = __builtin_bit_cast(unsigned int, f);
    unsigned int r = u + 0x7fffu + ((u >> 16) & 1u);
    return (u16)(r >> 16);
}

// ---------------------------------------------------------------------------
// Barrier-free, LDS-free streaming MFMA GEMM (split-K):
//   Cpart[sp][row][n] = sum_{k in chunk sp} A[row][k] * BT[n][k]
// Each wave owns an independent 16-row x 128-col output strip.
// Fragments loaded straight from global:
//   A-frag: lane(fm,quad) reads A[row0+fm][k+quad*8 .. +7] fp32, cvt->bf16
//   B-frag j: lane reads BT[j*16+fm][k+quad*8 .. +7] (bf16, one dwordx4)
// No __syncthreads anywhere -> latency hidden by outstanding loads + waves.
// ---------------------------------------------------------------------------
__global__ __launch_bounds__(256) void gemm_stream(const float* __restrict__ A, int lda,
                                                   const u16* __restrict__ BT, int ldbt,
                                                   float* __restrict__ Cpart,
                                                   int M, int K) {
    const int tid  = threadIdx.x;
    const int lane = tid & 63;
    const int fm   = lane & 15;
    const int quad = lane >> 4;
    const int ko   = quad * 8;
    const int wt   = blockIdx.x * 4 + (tid >> 6);  // wave-tile (16 rows)
    const int row0 = wt * 16;
    const int sp = blockIdx.y, nsp = gridDim.y;
    const int KT  = (K + 31) / 32;
    const int kt0 = (sp * KT) / nsp;
    const int kt1 = ((sp + 1) * KT) / nsp;

    int arow = row0 + fm;
    if (arow >= M) arow = M - 1;              // clamped lanes' output discarded
    const float* aptr = A + (size_t)arow * lda;
    const u16*   bptr = BT + (size_t)fm * ldbt;
    const size_t bstep = (size_t)16 * ldbt;

    const f32x4 zero = {0.f, 0.f, 0.f, 0.f};
    f32x4 acc[8];
#pragma unroll
    for (int j = 0; j < 8; j++) acc[j] = zero;

#pragma unroll 2
    for (int kt = kt0; kt < kt1; kt++) {
        const int k = kt * 32 + ko;
        // B fragments (8 x dwordx4 from L1/L2-resident BT)
        bf16x8 bq[8];
#pragma unroll
        for (int j = 0; j < 8; j++)
            bq[j] = *(const bf16x8*)(bptr + bstep * j + k);
        // A fragment (fp32 -> bf16). K is a multiple of 8, so the 8-element
        // lane read is either fully in-bounds or fully out.
        float4 a0 = make_float4(0.f, 0.f, 0.f, 0.f);
        float4 a1 = a0;
        if (k + 8 <= K) {
            a0 = *(const float4*)(aptr + k);
            a1 = *(const float4*)(aptr + k + 4);
        }
        u16 us[8];
        us[0] = f2bf(a0.x); us[1] = f2bf(a0.y); us[2] = f2bf(a0.z); us[3] = f2bf(a0.w);
        us[4] = f2bf(a1.x); us[5] = f2bf(a1.y); us[6] = f2bf(a1.z); us[7] = f2bf(a1.w);
        bf16x8 af = *(bf16x8*)us;
#pragma unroll
        for (int j = 0; j < 8; j++)
            acc[j] = __builtin_amdgcn_mfma_f32_16x16x32_bf16(af, bq[j], acc[j], 0, 0, 0);
    }

    float* op = Cpart + (size_t)sp * M * E_DIM;
#pragma unroll
    for (int r = 0; r < 4; r++) {
        int row = row0 + quad * 4 + r;
        if (row < M) {
#pragma unroll
            for (int j = 0; j < 8; j++)
                op[(size_t)row * E_DIM + j * 16 + fm] = acc[j][r];
        }
    }
}

// ---------------------------------------------------------------------------
// Small GEMM (K=128), BM=16: fuses the split-K reduction of its fp32 A input.
//   Ain[r][k] = pre( sum_s parts[s][r][k] )   pre: optional +preBias then relu
//   out[r][e] = act( Ain@W + bias )           act: 0=relu 1=hardshrink
// ---------------------------------------------------------------------------
__global__ __launch_bounds__(256) void gemm_small2(const float* __restrict__ parts,
                                                   int nparts, size_t partStride,
                                                   const float* __restrict__ preBias,
                                                   const float* __restrict__ W,
                                                   const float* __restrict__ bias,
                                                   float* __restrict__ outp,
                                                   int Mrows, int act) {
    __shared__ float Asum[16][132];
    const int tid = threadIdx.x;
    const int row0 = blockIdx.x * 16;
    const int r  = tid >> 4;
    const int kc = (tid & 15) * 8;
    const int grow = row0 + r;

    float4 s0 = make_float4(0.f, 0.f, 0.f, 0.f);
    float4 s1 = make_float4(0.f, 0.f, 0.f, 0.f);
    if (grow < Mrows) {
        for (int s = 0; s < nparts; s++) {
            const float* p = parts + (size_t)s * partStride + (size_t)grow * 128 + kc;
            float4 q0 = *(const float4*)p;
            float4 q1 = *(const float4*)(p + 4);
            s0.x += q0.x; s0.y += q0.y; s0.z += q0.z; s0.w += q0.w;
            s1.x += q1.x; s1.y += q1.y; s1.z += q1.z; s1.w += q1.w;
        }
        if (preBias != nullptr) {
            float4 pb0 = *(const float4*)(preBias + kc);
            float4 pb1 = *(const float4*)(preBias + kc + 4);
            s0.x = fmaxf(s0.x + pb0.x, 0.f); s0.y = fmaxf(s0.y + pb0.y, 0.f);
            s0.z = fmaxf(s0.z + pb0.z, 0.f); s0.w = fmaxf(s0.w + pb0.w, 0.f);
            s1.x = fmaxf(s1.x + pb1.x, 0.f); s1.y = fmaxf(s1.y + pb1.y, 0.f);
            s1.z = fmaxf(s1.z + pb1.z, 0.f); s1.w = fmaxf(s1.w + pb1.w, 0.f);
        }
    }
    *(float4*)&Asum[r][kc]     = s0;
    *(float4*)&Asum[r][kc + 4] = s1;
    __syncthreads();

    float acc[8];
#pragma unroll
    for (int j = 0; j < 8; j++) acc[j] = 0.f;
    const float* wp = W + kc;
#pragma unroll 4
    for (int k = 0; k < 128; k++) {
        float a = Asum[r][k];
        float4 w0 = *(const float4*)(wp + (size_t)k * 128);
        float4 w1 = *(const float4*)(wp + (size_t)k * 128 + 4);
        acc[0] += a * w0.x; acc[1] += a * w0.y;
        acc[2] += a * w0.z; acc[3] += a * w0.w;
        acc[4] += a * w1.x; acc[5] += a * w1.y;
        acc[6] += a * w1.z; acc[7] += a * w1.w;
    }
    if (grow < Mrows) {
        float4 bv0 = *(const float4*)(bias + kc);
        float4 bv1 = *(const float4*)(bias + kc + 4);
        float v[8];
        v[0] = acc[0] + bv0.x; v[1] = acc[1] + bv0.y;
        v[2] = acc[2] + bv0.z; v[3] = acc[3] + bv0.w;
        v[4] = acc[4] + bv1.x; v[5] = acc[5] + bv1.y;
        v[6] = acc[6] + bv1.z; v[7] = acc[7] + bv1.w;
#pragma unroll
        for (int j = 0; j < 8; j++)
            v[j] = (act == 0) ? fmaxf(v[j], 0.f) : hshrink(v[j]);
        float* op = outp + (size_t)grow * 128 + kc;
        *(float4*)op       = make_float4(v[0], v[1], v[2], v[3]);
        *(float4*)(op + 4) = make_float4(v[4], v[5], v[6], v[7]);
    }
}

// ---------------------------------------------------------------------------
__global__ void emb_copy(const float* __restrict__ embSe, float* __restrict__ x) {
    int i = blockIdx.x * blockDim.x + threadIdx.x;
    if (i < N_SE * E_DIM / 4)
        ((float4*)(x + (size_t)N_D * E_DIM))[i] = ((const float4*)embSe)[i];
}

// ---------------------------------------------------------------------------
// src [nrows][128] fp32 -> dst [128][kpad] bf16 (cols >= nrows zero-filled)
// grid: (kpad/64, 2)
// ---------------------------------------------------------------------------
__global__ __launch_bounds__(256) void transpose_bf16(const float* __restrict__ src,
                                                      u16* __restrict__ dst,
                                                      int nrows, int kpad) {
    __shared__ float t[64][65];
    const int r0 = blockIdx.x * 64;
    const int c0 = blockIdx.y * 64;
    const int tid = threadIdx.x;
    {
        const int i  = tid >> 4;          // 0..15
        const int cq = (tid & 15) * 4;
#pragma unroll
        for (int j = 0; j < 4; j++) {
            int r = r0 + i + j * 16;
            float4 v = make_float4(0.f, 0.f, 0.f, 0.f);
            if (r < nrows) v = *(const float4*)(src + (size_t)r * E_DIM + c0 + cq);
            t[i + j * 16][cq + 0] = v.x;
            t[i + j * 16][cq + 1] = v.y;
            t[i + j * 16][cq + 2] = v.z;
            t[i + j * 16][cq + 3] = v.w;
        }
    }
    __syncthreads();
    {
        const int ci = tid >> 2;          // 0..63
        const int rq = (tid & 3) * 16;
        u16 us[16];
#pragma unroll
        for (int j = 0; j < 16; j++) us[j] = f2bf(t[rq + j][ci]);
        u16* dp = dst + (size_t)(c0 + ci) * kpad + r0 + rq;
        *(uint4*)dp       = *(uint4*)&us[0];
        *(uint4*)(dp + 8) = *(uint4*)&us[8];
    }
}

// ---------------------------------------------------------------------------
// xs[r][e] = bf16( x[r][e] * rsd[r] )  — pre-scaled gather source for the head
// ---------------------------------------------------------------------------
__global__ __launch_bounds__(256) void scale_x_bf16(const float* __restrict__ x,
                                                    const float* __restrict__ rsd,
                                                    u16* __restrict__ xs) {
    int t = blockIdx.x * 256 + threadIdx.x;    // one thread per 8 elements
    if (t < N_TOT * (E_DIM / 8)) {
        int r = t >> 4;
        int c = (t & 15) * 8;
        float sc = rsd[r];
        const float* sp = x + (size_t)r * E_DIM + c;
        float4 v0 = *(const float4*)sp;
        float4 v1 = *(const float4*)(sp + 4);
        u16 us[8];
        us[0] = f2bf(v0.x * sc); us[1] = f2bf(v0.y * sc);
        us[2] = f2bf(v0.z * sc); us[3] = f2bf(v0.w * sc);
        us[4] = f2bf(v1.x * sc); us[5] = f2bf(v1.y * sc);
        us[6] = f2bf(v1.z * sc); us[7] = f2bf(v1.w * sc);
        *(uint4*)(xs + (size_t)r * E_DIM + c) = *(uint4*)us;
    }
}

// ---------------------------------------------------------------------------
// Head, barrier-free streaming: each wave owns 32 triples x 128 cols.
// A-frags gathered straight from pre-scaled bf16 xs rows (1 dwordx4/lane),
// B-frags streamed from L1/L2-resident Wp1T. Fused epilogue:
// u=HS(acc+bp1); s=sum_n u*Wp2[n]; out=HS(s+bp2), 16-lane shuffle reduction.
// ---------------------------------------------------------------------------
__global__ __launch_bounds__(256) void head_stream(const u16* __restrict__ xs,
                                                   const int* __restrict__ tpl,
                                                   const u16* __restrict__ Wp1T,
                                                   const float* __restrict__ bp1,
                                                   const float* __restrict__ Wp2,
                                                   const float* __restrict__ bp2,
                                                   float* __restrict__ outp) {
    const int tid  = threadIdx.x;
    const int lane = tid & 63;
    const int fm   = lane & 15;
    const int quad = lane >> 4;
    const int ko   = quad * 8;
    const int wt   = blockIdx.x * 4 + (tid >> 6);  // wave-tile (32 triples)
    const int m0   = wt * 32;

    // triple row indices for this lane's two m-fragments, all 3 segments
    int ma = m0 + fm;      if (ma >= M_TPL) ma = M_TPL - 1;
    int mb = m0 + 16 + fm; if (mb >= M_TPL) mb = M_TPL - 1;
    int r0s[3], r1s[3];
#pragma unroll
    for (int s = 0; s < 3; s++) {
        r0s[s] = tpl[ma * 3 + s];
        r1s[s] = tpl[mb * 3 + s];
    }

    const u16* bptr = Wp1T + (size_t)fm * 384;

    const f32x4 zero = {0.f, 0.f, 0.f, 0.f};
    f32x4 acc0[8], acc1[8];
#pragma unroll
    for (int j = 0; j < 8; j++) { acc0[j] = zero; acc1[j] = zero; }

#pragma unroll 4
    for (int kt = 0; kt < 12; kt++) {
        const int seg = kt >> 2;
        const int k   = kt * 32 + ko;            // col within Wp1T row (0..383)
        const int kc  = (kt & 3) * 32 + ko;      // col within xs row (0..127)
        bf16x8 a0 = *(const bf16x8*)(xs + (size_t)r0s[seg] * E_DIM + kc);
        bf16x8 a1 = *(const bf16x8*)(xs + (size_t)r1s[seg] * E_DIM + kc);
#pragma unroll
        for (int j = 0; j < 8; j++) {
            bf16x8 b = *(const bf16x8*)(bptr + (size_t)j * 16 * 384 + k);
            acc0[j] = __builtin_amdgcn_mfma_f32_16x16x32_bf16(a0, b, acc0[j], 0, 0, 0);
            acc1[j] = __builtin_amdgcn_mfma_f32_16x16x32_bf16(a1, b, acc1[j], 0, 0, 0);
        }
    }

    float bp1v[8], wp2v[8];
#pragma unroll
    for (int j = 0; j < 8; j++) {
        int n = j * 16 + fm;
        bp1v[j] = bp1[n];
        wp2v[j] = Wp2[n];
    }
    float b2 = bp2[0];
#pragma unroll
    for (int half = 0; half < 2; half++) {
        f32x4* ac = half ? acc1 : acc0;
#pragma unroll
        for (int r = 0; r < 4; r++) {
            float p = 0.f;
#pragma unroll
            for (int j = 0; j < 8; j++)
                p += hshrink(ac[j][r] + bp1v[j]) * wp2v[j];
            p += __shfl_xor(p, 1, 64);
            p += __shfl_xor(p, 2, 64);
            p += __shfl_xor(p, 4, 64);
            p += __shfl_xor(p, 8, 64);
            int m = m0 + half * 16 + quad * 4 + r;
            if (fm == 0 && m < M_TPL)
                outp[m] = hshrink(p + b2);
        }
    }
}

// ---------------------------------------------------------------------------
extern "C" void kernel_launch(void* const* d_in, const int* in_sizes, int n_in,
                              void* d_out, int out_size, void* d_ws, size_t ws_size,
                              hipStream_t stream) {
    const float* drugF = (const float*)d_in[0];
    const float* A     = (const float*)d_in[1];
    const int*   tpl   = (const int*)d_in[2];
    const float* rsd   = (const float*)d_in[3];
    const float* W1    = (const float*)d_in[4];
    const float* b1    = (const float*)d_in[5];
    const float* W2    = (const float*)d_in[6];
    const float* b2    = (const float*)d_in[7];
    const float* embSe = (const float*)d_in[8];
    const float* Wl    = (const float*)d_in[9];
    const float* bl    = (const float*)d_in[10];
    const float* Wp1   = (const float*)d_in[11];
    const float* bp1   = (const float*)d_in[12];
    const float* Wp2   = (const float*)d_in[13];
    const float* bp2   = (const float*)d_in[14];
    float* outp = (float*)d_out;

    float* ws = (float*)d_ws;
    const size_t XSZ = (size_t)N_TOT * E_DIM;   // 896000 floats
    // fixed bf16 blocks: xT + W1T + Wp1T + xs
    const size_t fixedB = ((size_t)128 * KPAD + (size_t)128 * 1024 +
                           (size_t)128 * 384 + XSZ) * 2;
    int SPL = 2;
    {
        const int cands[4] = {12, 8, 4, 2};
        for (int ci = 0; ci < 4; ci++) {
            int s = cands[ci];
            if (ws_size >= XSZ * 4 * (size_t)(1 + s) + fixedB) { SPL = s; break; }
        }
    }
    float* x     = ws;
    float* parts = ws + XSZ;
    u16* xT   = (u16*)(ws + XSZ * (size_t)(1 + SPL));
    u16* W1T  = xT  + (size_t)128 * KPAD;
    u16* Wp1T = W1T + (size_t)128 * 1024;
    u16* xs   = Wp1T + (size_t)128 * 384;

    // 0) weight conversions
    transpose_bf16<<<dim3(1024 / 64, 2), 256, 0, stream>>>(W1, W1T, F_SIZE, 1024);
    transpose_bf16<<<dim3(384 / 64, 2), 256, 0, stream>>>(Wp1, Wp1T, 384, 384);
    // 1) MLP layer 1 (streaming bf16 MFMA split-K) + fused-reduce MLP layer 2
    gemm_stream<<<dim3((N_D / 16 + 3) / 4, SPL), 256, 0, stream>>>(
        drugF, F_SIZE, W1T, 1024, parts, N_D, F_SIZE);
    gemm_small2<<<dim3((N_D + 15) / 16), 256, 0, stream>>>(
        parts, SPL, (size_t)N_D * E_DIM, b1, W2, b2, x, N_D, 0);
    // 2) embSe rows
    emb_copy<<<dim3((N_SE * E_DIM / 4 + 255) / 256), 256, 0, stream>>>(embSe, x);
    // 3) two propagation layers: x = HS( (A@x) @ Wl[i] + bl[i] )
    for (int l = 0; l < 2; l++) {
        transpose_bf16<<<dim3(KPAD / 64, 2), 256, 0, stream>>>(x, xT, N_TOT, KPAD);
        gemm_stream<<<dim3(((N_TOT + 15) / 16 + 3) / 4, SPL), 256, 0, stream>>>(
            A, N_TOT, xT, KPAD, parts, N_TOT, N_TOT);
        gemm_small2<<<dim3((N_TOT + 15) / 16), 256, 0, stream>>>(
            parts, SPL, XSZ, nullptr,
            Wl + (size_t)l * E_DIM * E_DIM, bl + (size_t)l * E_DIM, x, N_TOT, 1);
    }
    // 4) pre-scaled bf16 gather source, then head
    scale_x_bf16<<<dim3((N_TOT * (E_DIM / 8) + 255) / 256), 256, 0, stream>>>(
        x, rsd, xs);
    head_stream<<<dim3(((M_TPL + 31) / 32 + 3) / 4), 256, 0, stream>>>(
        xs, tpl, Wp1T, bp1, Wp2, bp2, outp);
}

// Round 6
// 532.521 us; speedup vs baseline: 1.4277x; 1.4277x over previous
//
#include <hip/hip_runtime.h>
#include <hip/hip_bf16.h>

// Problem constants (from reference setup_inputs)
#define F_SIZE 1024
#define E_DIM  128
#define N_D    6000
#define N_SE   1000
#define N_TOT  7000
#define M_TPL  300000
#define LAMB   1e-6f
#define KPAD   7040   // N_TOT rounded up (xT leading dim)
#define SPL_AX  7     // split-K for A@x: 110 x-tiles * 7 = 770 blocks (3.0/CU)
#define SPL_MLP 8     // split-K for MLP1: 94 * 8 = 752 blocks

typedef __bf16 bf16x8 __attribute__((ext_vector_type(8)));
typedef float  f32x4  __attribute__((ext_vector_type(4)));
typedef unsigned short u16;

__device__ __forceinline__ float hshrink(float v) {
    return fabsf(v) > LAMB ? v : 0.0f;
}

// RNE float -> bf16 bits (inputs are finite; no NaN handling needed)
__device__ __forceinline__ u16 f2bf(float f) {
    unsigned int u = __builtin_bit_cast(unsigned int, f);
    unsigned int r = u + 0x7fffu + ((u >> 16) & 1u);
    return (u16)(r >> 16);
}

// Async global->LDS DMA, 16B per lane. LDS dest must be wave-uniform;
// each lane deposits at ldsbase + lane*16. Global per-lane address arbitrary.
__device__ __forceinline__ void gl_lds16(const void* g, void* l) {
    __builtin_amdgcn_global_load_lds(
        (__attribute__((address_space(1))) void*)(void*)(g),
        (__attribute__((address_space(3))) void*)(l), 16, 0, 0);
}

// ---------------------------------------------------------------------------
// m97-style MFMA GEMM, split-K:
//   Cpart[sp][row][n] = sum_{k chunk} A[row][k] * BT[n][k]
// A fp32 [M][lda] staged raw into LDS via global_load_lds (cvt at frag read).
// BT bf16 [128][ldbt] (zero-padded cols). BM=64, BN=128, BK=32.
// 2-barrier K-loop: barrier / DMA-stage / barrier / ds_read+MFMA.
// LDS lane->chunk mapping is XOR-swizzled so frag ds_reads are ~2-way only:
//   As (128B rows, 8 chunks):  LDS(r,j) = global(r, j ^ (r&7))
//   Bs (64B rows, 4 chunks):   LDS(n,j) = global(n, j ^ ((n>>1)&3))
// ---------------------------------------------------------------------------
__global__ __launch_bounds__(256) void gemm_dma(const float* __restrict__ A, int lda,
                                                const u16* __restrict__ BT, int ldbt,
                                                float* __restrict__ Cpart,
                                                int M, int K) {
    __shared__ float As[64 * 32];    // 8 KB
    __shared__ u16   Bs[128 * 32];   // 8 KB
    const int tid  = threadIdx.x;
    const int lane = tid & 63;
    const int w    = tid >> 6;
    const int fm   = lane & 15;
    const int quad = lane >> 4;
    const int wm   = (w & 1) * 32;
    const int wn   = (w >> 1) * 64;
    const int row0 = blockIdx.x * 64;
    const int sp = blockIdx.y, nsp = gridDim.y;
    const int KT  = (K + 31) / 32;
    const int kt0 = sp * KT / nsp;
    const int kt1 = (sp + 1) * KT / nsp;

    // A staging: wave w stages local rows [w*16, w*16+16), 2 instr x 8 rows.
    int aLoc[2], aQ[2];
    const float* aG[2];
#pragma unroll
    for (int j = 0; j < 2; j++) {
        int r = w * 16 + j * 8 + (lane >> 3);   // local row 0..63
        aLoc[j] = r;
        int grow = row0 + r; if (grow > M - 1) grow = M - 1;
        aQ[j] = (lane & 7) ^ (r & 7);
        aG[j] = A + (size_t)grow * lda + aQ[j] * 4;
    }
    // B staging: wave w stages rows [w*32, w*32+32), 2 instr x 16 rows.
    const u16* bG[2];
#pragma unroll
    for (int j = 0; j < 2; j++) {
        int n = w * 32 + j * 16 + (lane >> 2);
        int q = (lane & 3) ^ ((n >> 1) & 3);
        bG[j] = BT + (size_t)n * ldbt + q * 8;
    }

    const f32x4 zero = {0.f, 0.f, 0.f, 0.f};
    f32x4 acc[2][4];
#pragma unroll
    for (int i = 0; i < 2; i++)
#pragma unroll
        for (int j = 0; j < 4; j++) acc[i][j] = zero;

    for (int kt = kt0; kt < kt1; kt++) {
        const int k0 = kt * 32;
        __syncthreads();                    // previous compute done with LDS
        if (k0 + 32 <= K) {
#pragma unroll
            for (int j = 0; j < 2; j++)
                gl_lds16(aG[j] + k0, &As[(w * 16 + j * 8) * 32]);
        } else {
            // masked tail tile (K not multiple of 32; chunks are 4-aligned)
#pragma unroll
            for (int j = 0; j < 2; j++) {
                float4 v = make_float4(0.f, 0.f, 0.f, 0.f);
                if (k0 + aQ[j] * 4 + 4 <= K) v = *(const float4*)(aG[j] + k0);
                *(float4*)&As[aLoc[j] * 32 + (lane & 7) * 4] = v;
            }
        }
#pragma unroll
        for (int j = 0; j < 2; j++)
            gl_lds16(bG[j] + k0, &Bs[(w * 32 + j * 16) * 32]);
        __syncthreads();                    // DMA landed (vmcnt drain)

        bf16x8 bfr[4];
#pragma unroll
        for (int ni = 0; ni < 4; ni++) {
            int n = wn + ni * 16 + fm;
            bfr[ni] = *(const bf16x8*)&Bs[n * 32 + (quad ^ ((n >> 1) & 3)) * 8];
        }
#pragma unroll
        for (int mi = 0; mi < 2; mi++) {
            int r = wm + mi * 16 + fm;
            int s = r & 7;
            f32x4 f0 = *(const f32x4*)&As[r * 32 + ((quad * 2) ^ s) * 4];
            f32x4 f1 = *(const f32x4*)&As[r * 32 + ((quad * 2 + 1) ^ s) * 4];
            u16 us[8];
            us[0] = f2bf(f0[0]); us[1] = f2bf(f0[1]);
            us[2] = f2bf(f0[2]); us[3] = f2bf(f0[3]);
            us[4] = f2bf(f1[0]); us[5] = f2bf(f1[1]);
            us[6] = f2bf(f1[2]); us[7] = f2bf(f1[3]);
            bf16x8 af = *(bf16x8*)us;
#pragma unroll
            for (int ni = 0; ni < 4; ni++)
                acc[mi][ni] = __builtin_amdgcn_mfma_f32_16x16x32_bf16(
                    af, bfr[ni], acc[mi][ni], 0, 0, 0);
        }
    }

    float* op = Cpart + (size_t)sp * M * E_DIM;
#pragma unroll
    for (int mi = 0; mi < 2; mi++) {
#pragma unroll
        for (int rr = 0; rr < 4; rr++) {
            int row = row0 + wm + mi * 16 + quad * 4 + rr;
            if (row < M) {
#pragma unroll
                for (int ni = 0; ni < 4; ni++)
                    op[(size_t)row * E_DIM + wn + ni * 16 + fm] = acc[mi][ni][rr];
            }
        }
    }
}

// ---------------------------------------------------------------------------
// Small GEMM (K=128), BM=16: fuses the split-K reduction of its fp32 A input.
// ---------------------------------------------------------------------------
__global__ __launch_bounds__(256) void gemm_small2(const float* __restrict__ parts,
                                                   int nparts, size_t partStride,
                                                   const float* __restrict__ preBias,
                                                   const float* __restrict__ W,
                                                   const float* __restrict__ bias,
                                                   float* __restrict__ outp,
                                                   int Mrows, int act) {
    __shared__ float Asum[16][132];
    const int tid = threadIdx.x;
    const int row0 = blockIdx.x * 16;
    const int r  = tid >> 4;
    const int kc = (tid & 15) * 8;
    const int grow = row0 + r;

    float4 s0 = make_float4(0.f, 0.f, 0.f, 0.f);
    float4 s1 = make_float4(0.f, 0.f, 0.f, 0.f);
    if (grow < Mrows) {
        for (int s = 0; s < nparts; s++) {
            const float* p = parts + (size_t)s * partStride + (size_t)grow * 128 + kc;
            float4 q0 = *(const float4*)p;
            float4 q1 = *(const float4*)(p + 4);
            s0.x += q0.x; s0.y += q0.y; s0.z += q0.z; s0.w += q0.w;
            s1.x += q1.x; s1.y += q1.y; s1.z += q1.z; s1.w += q1.w;
        }
        if (preBias != nullptr) {
            float4 pb0 = *(const float4*)(preBias + kc);
            float4 pb1 = *(const float4*)(preBias + kc + 4);
            s0.x = fmaxf(s0.x + pb0.x, 0.f); s0.y = fmaxf(s0.y + pb0.y, 0.f);
            s0.z = fmaxf(s0.z + pb0.z, 0.f); s0.w = fmaxf(s0.w + pb0.w, 0.f);
            s1.x = fmaxf(s1.x + pb1.x, 0.f); s1.y = fmaxf(s1.y + pb1.y, 0.f);
            s1.z = fmaxf(s1.z + pb1.z, 0.f); s1.w = fmaxf(s1.w + pb1.w, 0.f);
        }
    }
    *(float4*)&Asum[r][kc]     = s0;
    *(float4*)&Asum[r][kc + 4] = s1;
    __syncthreads();

    float acc[8];
#pragma unroll
    for (int j = 0; j < 8; j++) acc[j] = 0.f;
    const float* wp = W + kc;
#pragma unroll 4
    for (int k = 0; k < 128; k++) {
        float a = Asum[r][k];
        float4 w0 = *(const float4*)(wp + (size_t)k * 128);
        float4 w1 = *(const float4*)(wp + (size_t)k * 128 + 4);
        acc[0] += a * w0.x; acc[1] += a * w0.y;
        acc[2] += a * w0.z; acc[3] += a * w0.w;
        acc[4] += a * w1.x; acc[5] += a * w1.y;
        acc[6] += a * w1.z; acc[7] += a * w1.w;
    }
    if (grow < Mrows) {
        float4 bv0 = *(const float4*)(bias + kc);
        float4 bv1 = *(const float4*)(bias + kc + 4);
        float v[8];
        v[0] = acc[0] + bv0.x; v[1] = acc[1] + bv0.y;
        v[2] = acc[2] + bv0.z; v[3] = acc[3] + bv0.w;
        v[4] = acc[4] + bv1.x; v[5] = acc[5] + bv1.y;
        v[6] = acc[6] + bv1.z; v[7] = acc[7] + bv1.w;
#pragma unroll
        for (int j = 0; j < 8; j++)
            v[j] = (act == 0) ? fmaxf(v[j], 0.f) : hshrink(v[j]);
        float* op = outp + (size_t)grow * 128 + kc;
        *(float4*)op       = make_float4(v[0], v[1], v[2], v[3]);
        *(float4*)(op + 4) = make_float4(v[4], v[5], v[6], v[7]);
    }
}

// ---------------------------------------------------------------------------
__global__ void emb_copy(const float* __restrict__ embSe, float* __restrict__ x) {
    int i = blockIdx.x * blockDim.x + threadIdx.x;
    if (i < N_SE * E_DIM / 4)
        ((float4*)(x + (size_t)N_D * E_DIM))[i] = ((const float4*)embSe)[i];
}

// ---------------------------------------------------------------------------
// src [nrows][128] fp32 -> dst [128][kpad] bf16 (cols >= nrows zero-filled)
// grid: (kpad/64, 2)
// ---------------------------------------------------------------------------
__global__ __launch_bounds__(256) void transpose_bf16(const float* __restrict__ src,
                                                      u16* __restrict__ dst,
                                                      int nrows, int kpad) {
    __shared__ float t[64][65];
    const int r0 = blockIdx.x * 64;
    const int c0 = blockIdx.y * 64;
    const int tid = threadIdx.x;
    {
        const int i  = tid >> 4;          // 0..15
        const int cq = (tid & 15) * 4;
#pragma unroll
        for (int j = 0; j < 4; j++) {
            int r = r0 + i + j * 16;
            float4 v = make_float4(0.f, 0.f, 0.f, 0.f);
            if (r < nrows) v = *(const float4*)(src + (size_t)r * E_DIM + c0 + cq);
            t[i + j * 16][cq + 0] = v.x;
            t[i + j * 16][cq + 1] = v.y;
            t[i + j * 16][cq + 2] = v.z;
            t[i + j * 16][cq + 3] = v.w;
        }
    }
    __syncthreads();
    {
        const int ci = tid >> 2;          // 0..63
        const int rq = (tid & 3) * 16;
        u16 us[16];
#pragma unroll
        for (int j = 0; j < 16; j++) us[j] = f2bf(t[rq + j][ci]);
        u16* dp = dst + (size_t)(c0 + ci) * kpad + r0 + rq;
        *(uint4*)dp       = *(uint4*)&us[0];
        *(uint4*)(dp + 8) = *(uint4*)&us[8];
    }
}

// ---------------------------------------------------------------------------
// xs[r][e] = bf16( x[r][e] * rsd[r] )  — pre-scaled gather source for the head
// ---------------------------------------------------------------------------
__global__ __launch_bounds__(256) void scale_x_bf16(const float* __restrict__ x,
                                                    const float* __restrict__ rsd,
                                                    u16* __restrict__ xs) {
    int t = blockIdx.x * 256 + threadIdx.x;    // one thread per 8 elements
    if (t < N_TOT * (E_DIM / 8)) {
        int r = t >> 4;
        int c = (t & 15) * 8;
        float sc = rsd[r];
        const float* sp = x + (size_t)r * E_DIM + c;
        float4 v0 = *(const float4*)sp;
        float4 v1 = *(const float4*)(sp + 4);
        u16 us[8];
        us[0] = f2bf(v0.x * sc); us[1] = f2bf(v0.y * sc);
        us[2] = f2bf(v0.z * sc); us[3] = f2bf(v0.w * sc);
        us[4] = f2bf(v1.x * sc); us[5] = f2bf(v1.y * sc);
        us[6] = f2bf(v1.z * sc); us[7] = f2bf(v1.w * sc);
        *(uint4*)(xs + (size_t)r * E_DIM + c) = *(uint4*)us;
    }
}

// ---------------------------------------------------------------------------
// Head, m97 structure: 128 triples/block, 12 k-tiles of 32.
// A-tile = gathered xs rows (per-lane DMA gather!), B-tile = Wp1T; both bf16,
// same XOR swizzle as gemm_dma's Bs. Fused HS->dot(Wp2)->HS epilogue.
// ---------------------------------------------------------------------------
__global__ __launch_bounds__(256) void head_dma(const u16* __restrict__ xs,
                                                const int* __restrict__ tpl,
                                                const u16* __restrict__ Wp1T,
                                                const float* __restrict__ bp1,
                                                const float* __restrict__ Wp2,
                                                const float* __restrict__ bp2,
                                                float* __restrict__ outp) {
    __shared__ u16 As[128 * 32];    // 8 KB
    __shared__ u16 Bs[128 * 32];    // 8 KB
    __shared__ float sred[2][128];
    const int tid  = threadIdx.x;
    const int lane = tid & 63;
    const int w    = tid >> 6;
    const int fm   = lane & 15;
    const int quad = lane >> 4;
    const int wm   = (w & 1) * 64;
    const int wn   = (w >> 1) * 64;
    const int m0   = blockIdx.x * 128;

    // A staging: wave w gathers local triples [w*32, w*32+32), 2 instr x 16.
    int aQ8[2];
    int rid[2][3];
#pragma unroll
    for (int j = 0; j < 2; j++) {
        int ml = w * 32 + j * 16 + (lane >> 2);     // local triple 0..127
        int gm = m0 + ml; if (gm > M_TPL - 1) gm = M_TPL - 1;
        aQ8[j] = ((lane & 3) ^ ((ml >> 1) & 3)) * 8;
#pragma unroll
        for (int s = 0; s < 3; s++) rid[j][s] = tpl[gm * 3 + s];
    }
    // B staging
    const u16* bG[2];
#pragma unroll
    for (int j = 0; j < 2; j++) {
        int n = w * 32 + j * 16 + (lane >> 2);
        int q = (lane & 3) ^ ((n >> 1) & 3);
        bG[j] = Wp1T + (size_t)n * 384 + q * 8;
    }

    const f32x4 zero = {0.f, 0.f, 0.f, 0.f};
    f32x4 acc[4][4];
#pragma unroll
    for (int i = 0; i < 4; i++)
#pragma unroll
        for (int j = 0; j < 4; j++) acc[i][j] = zero;

    for (int kt = 0; kt < 12; kt++) {
        const int seg = kt >> 2;
        const int kc0 = (kt & 3) * 32;
        const int k0  = kt * 32;
        __syncthreads();
#pragma unroll
        for (int j = 0; j < 2; j++)
            gl_lds16(xs + (size_t)rid[j][seg] * E_DIM + kc0 + aQ8[j],
                     &As[(w * 32 + j * 16) * 32]);
#pragma unroll
        for (int j = 0; j < 2; j++)
            gl_lds16(bG[j] + k0, &Bs[(w * 32 + j * 16) * 32]);
        __syncthreads();

        bf16x8 af[4], bfv[4];
#pragma unroll
        for (int i = 0; i < 4; i++) {
            int r = wm + i * 16 + fm;
            int n = wn + i * 16 + fm;
            af[i]  = *(const bf16x8*)&As[r * 32 + (quad ^ ((r >> 1) & 3)) * 8];
            bfv[i] = *(const bf16x8*)&Bs[n * 32 + (quad ^ ((n >> 1) & 3)) * 8];
        }
#pragma unroll
        for (int mi = 0; mi < 4; mi++)
#pragma unroll
            for (int ni = 0; ni < 4; ni++)
                acc[mi][ni] = __builtin_amdgcn_mfma_f32_16x16x32_bf16(
                    af[mi], bfv[ni], acc[mi][ni], 0, 0, 0);
    }

    // epilogue: u=HS(acc+bp1); s=sum_n u*Wp2[n]; out=HS(s+bp2)
    float bp1v[4], wp2v[4];
#pragma unroll
    for (int ni = 0; ni < 4; ni++) {
        int n = wn + ni * 16 + fm;
        bp1v[ni] = bp1[n];
        wp2v[ni] = Wp2[n];
    }
#pragma unroll
    for (int mi = 0; mi < 4; mi++) {
#pragma unroll
        for (int rr = 0; rr < 4; rr++) {
            float p = 0.f;
#pragma unroll
            for (int ni = 0; ni < 4; ni++)
                p += hshrink(acc[mi][ni][rr] + bp1v[ni]) * wp2v[ni];
            p += __shfl_xor(p, 1, 64);
            p += __shfl_xor(p, 2, 64);
            p += __shfl_xor(p, 4, 64);
            p += __shfl_xor(p, 8, 64);
            if (fm == 0)
                sred[wn >> 6][wm + mi * 16 + quad * 4 + rr] = p;
        }
    }
    __syncthreads();
    if (tid < 128) {
        int gm = m0 + tid;
        if (gm < M_TPL)
            outp[gm] = hshrink(sred[0][tid] + sred[1][tid] + bp2[0]);
    }
}

// ---------------------------------------------------------------------------
extern "C" void kernel_launch(void* const* d_in, const int* in_sizes, int n_in,
                              void* d_out, int out_size, void* d_ws, size_t ws_size,
                              hipStream_t stream) {
    const float* drugF = (const float*)d_in[0];
    const float* A     = (const float*)d_in[1];
    const int*   tpl   = (const int*)d_in[2];
    const float* rsd   = (const float*)d_in[3];
    const float* W1    = (const float*)d_in[4];
    const float* b1    = (const float*)d_in[5];
    const float* W2    = (const float*)d_in[6];
    const float* b2    = (const float*)d_in[7];
    const float* embSe = (const float*)d_in[8];
    const float* Wl    = (const float*)d_in[9];
    const float* bl    = (const float*)d_in[10];
    const float* Wp1   = (const float*)d_in[11];
    const float* bp1   = (const float*)d_in[12];
    const float* Wp2   = (const float*)d_in[13];
    const float* bp2   = (const float*)d_in[14];
    float* outp = (float*)d_out;

    float* ws = (float*)d_ws;
    const size_t XSZ = (size_t)N_TOT * E_DIM;   // 896000 floats
    // parts sized for the larger of SPL_AX*N_TOT and SPL_MLP*N_D row-sets
    const size_t PARTS = (size_t)SPL_AX * XSZ > (size_t)SPL_MLP * N_D * E_DIM
                             ? (size_t)SPL_AX * XSZ
                             : (size_t)SPL_MLP * N_D * E_DIM;
    float* x     = ws;
    float* parts = ws + XSZ;
    u16* xT   = (u16*)(ws + XSZ + PARTS);
    u16* W1T  = xT  + (size_t)128 * KPAD;
    u16* Wp1T = W1T + (size_t)128 * 1024;
    u16* xs   = Wp1T + (size_t)128 * 384;

    // 0) weight conversions
    transpose_bf16<<<dim3(1024 / 64, 2), 256, 0, stream>>>(W1, W1T, F_SIZE, 1024);
    transpose_bf16<<<dim3(384 / 64, 2), 256, 0, stream>>>(Wp1, Wp1T, 384, 384);
    // 1) MLP layer 1 (DMA-staged bf16 MFMA split-K) + fused-reduce MLP layer 2
    gemm_dma<<<dim3((N_D + 63) / 64, SPL_MLP), 256, 0, stream>>>(
        drugF, F_SIZE, W1T, 1024, parts, N_D, F_SIZE);
    gemm_small2<<<dim3((N_D + 15) / 16), 256, 0, stream>>>(
        parts, SPL_MLP, (size_t)N_D * E_DIM, b1, W2, b2, x, N_D, 0);
    // 2) embSe rows
    emb_copy<<<dim3((N_SE * E_DIM / 4 + 255) / 256), 256, 0, stream>>>(embSe, x);
    // 3) two propagation layers: x = HS( (A@x) @ Wl[i] + bl[i] )
    for (int l = 0; l < 2; l++) {
        transpose_bf16<<<dim3(KPAD / 64, 2), 256, 0, stream>>>(x, xT, N_TOT, KPAD);
        gemm_dma<<<dim3((N_TOT + 63) / 64, SPL_AX), 256, 0, stream>>>(
            A, N_TOT, xT, KPAD, parts, N_TOT, N_TOT);
        gemm_small2<<<dim3((N_TOT + 15) / 16), 256, 0, stream>>>(
            parts, SPL_AX, XSZ, nullptr,
            Wl + (size_t)l * E_DIM * E_DIM, bl + (size_t)l * E_DIM, x, N_TOT, 1);
    }
    // 4) pre-scaled bf16 gather source, then head
    scale_x_bf16<<<dim3((N_TOT * (E_DIM / 8) + 255) / 256), 256, 0, stream>>>(
        x, rsd, xs);
    head_dma<<<dim3((M_TPL + 127) / 128), 256, 0, stream>>>(
        xs, tpl, Wp1T, bp1, Wp2, bp2, outp);
}